// Round 17
// baseline (433.721 us; speedup 1.0000x reference)
//
#include <hip/hip_runtime.h>

#define CH 128
// fold 1/sqrt(32) * log2(e) into Wq/bq so Q·K dots come out in base-2 directly
#define QSCALE (0.17677669529663687f * 1.4426950408889634f)
#define LOG2E 1.4426950408889634f
#define SCAN_BLK 1024
#define KVSTRIDE 384   // per-node row: K (128 fp8 = 128B) | V (128 f16 = 256B)
#define QROWS 32       // qkv tile rows
#define WCVT_BLOCKS 192  // 3*128*128/256

typedef _Float16 f16;
typedef _Float16 f16x2 __attribute__((ext_vector_type(2)));
typedef _Float16 f16x8 __attribute__((ext_vector_type(8)));
typedef __attribute__((ext_vector_type(4))) float f32x4;

__device__ __forceinline__ unsigned pk2(float a, float b) {
    auto h = __builtin_amdgcn_cvt_pkrtz(a, b);     // __fp16 ext_vector(2)
    return __builtin_bit_cast(unsigned, h);
}
__device__ __forceinline__ f16x2 u2h(unsigned u) { return __builtin_bit_cast(f16x2, u); }

template <int CTRL>
__device__ __forceinline__ float dpp_add(float x) {
    const int t = __builtin_amdgcn_update_dpp(0, __builtin_bit_cast(int, x), CTRL, 0xF, 0xF, false);
    return x + __builtin_bit_cast(float, t);
}
// sum over the 16-lane head group (2 ch/lane x 16 lanes = 32 ch)
__device__ __forceinline__ float head_sum(float x) {
    x = dpp_add<0xB1>(x);    // quad_perm(1,0,3,2)
    x = dpp_add<0x4E>(x);    // quad_perm(2,3,0,1)
    x = dpp_add<0x124>(x);   // row_ror:4
    x = dpp_add<0x128>(x);   // row_ror:8
    return x;
}

// ======================= shared device bodies =======================

// csr_fill body for ONE direction: scatter (src*KVSTRIDE, (sb+bias)*log2e) dst-sorted.
__device__ __forceinline__ void csr_body(int ridx, const int* __restrict__ ei,
                                         const float* __restrict__ sb, float bia,
                                         int* __restrict__ cur, int2* __restrict__ ed, int nE)
{
    const int e = (ridx * 256 + threadIdx.x) * 4;
    if (e >= nE) return;
    if (e + 3 < nE) {
        const int4 s4 = *(const int4*)(ei + e);
        const int4 d4 = *(const int4*)(ei + nE + e);
        const float4 b4 = *(const float4*)(sb + e);
        int p0 = atomicAdd(&cur[d4.x], 1); ed[p0] = make_int2(s4.x * KVSTRIDE, __float_as_int((b4.x + bia) * LOG2E));
        int p1 = atomicAdd(&cur[d4.y], 1); ed[p1] = make_int2(s4.y * KVSTRIDE, __float_as_int((b4.y + bia) * LOG2E));
        int p2 = atomicAdd(&cur[d4.z], 1); ed[p2] = make_int2(s4.z * KVSTRIDE, __float_as_int((b4.z + bia) * LOG2E));
        int p3 = atomicAdd(&cur[d4.w], 1); ed[p3] = make_int2(s4.w * KVSTRIDE, __float_as_int((b4.w + bia) * LOG2E));
    } else {
        for (int j = e; j < nE; ++j) {
            const int pos = atomicAdd(&cur[ei[nE + j]], 1);
            ed[pos] = make_int2(ei[j] * KVSTRIDE, __float_as_int((sb[j] + bia) * LOG2E));
        }
    }
}

// attn body for ONE direction: 1 node/wave, 2 ch/lane, 8-deep ping-pong prefetch,
// wave-uniform branchy loads, mid-loop early-exit. K fp8, V f16, base-2 online softmax
// with defer-max. Degree term cancels in LN mean subtraction.
__device__ __forceinline__ void attn_body(int nblk,
    const unsigned short* __restrict__ Q, const unsigned char* __restrict__ KV,
    const float* __restrict__ x, const int* __restrict__ offs, const int* __restrict__ deg,
    const int2* __restrict__ ed, const float* __restrict__ gamma, const float* __restrict__ beta,
    float* __restrict__ o, int n)
{
    const int node = nblk * 4 + (threadIdx.x >> 6);
    if (node >= n) return;
    const int l = threadIdx.x & 63;
    const int l2 = l * 2;

    const f16x2 qp = u2h(*(const unsigned*)(Q + (size_t)node * CH + l2));
    const float qf0 = (float)qp[0], qf1 = (float)qp[1];

    const int beg = __builtin_amdgcn_readfirstlane(offs[node]);
    const int d   = __builtin_amdgcn_readfirstlane(deg[node]);

    float m = -3.0e38f, den = 0.f;
    f16x2 a01 = (f16x2){(f16)0.f, (f16)0.f};

    auto loadE = [&](int i, float& sbf, unsigned& kc, unsigned& vc) {
        if (i < d) {                                   // wave-uniform -> scalar branch
            const int2 e = ed[beg + i];
            sbf = __int_as_float(e.y);
            const unsigned b = (unsigned)e.x;          // premultiplied byte offset
            kc = *(const unsigned short*)(KV + b + l2);        // 2 fp8
            vc = *(const unsigned*)(KV + b + 128 + l2 * 2);    // 2 f16
        } else {
            sbf = __int_as_float((int)0xFF800000u);    // -inf -> zero contribution
            kc = 0; vc = 0;
        }
    };

    auto procPair = [&](float sf0, unsigned k0, unsigned v0,
                        float sf1, unsigned k1, unsigned v1) {
        const auto kf0 = __builtin_amdgcn_cvt_pk_f32_fp8((int)k0, false);
        const auto kf1 = __builtin_amdgcn_cvt_pk_f32_fp8((int)k1, false);
        float sa = head_sum(fmaf(qf0, kf0[0], qf1 * kf0[1])) + sf0;
        float sb = head_sum(fmaf(qf0, kf1[0], qf1 * kf1[1])) + sf1;
        const float pm = fmaxf(sa, sb);
        if (!__all(pm <= m + 8.f)) {           // defer-max
            const float mn = fmaxf(m, pm);
            const float sc = exp2f(m - mn);
            den *= sc;
            a01 *= u2h(pk2(sc, sc));
            m = mn;
        }
        const float ea = exp2f(sa - m);
        const float eb = exp2f(sb - m);
        den += ea + eb;
        a01 += u2h(pk2(ea, ea)) * u2h(v0);
        a01 += u2h(pk2(eb, eb)) * u2h(v1);
    };

    float sA0, sA1, sA2, sA3, sB0, sB1, sB2, sB3;
    unsigned kA0, kA1, kA2, kA3, kB0, kB1, kB2, kB3;
    unsigned vA0, vA1, vA2, vA3, vB0, vB1, vB2, vB3;
    loadE(0, sA0, kA0, vA0); loadE(1, sA1, kA1, vA1);
    loadE(2, sA2, kA2, vA2); loadE(3, sA3, kA3, vA3);
    loadE(4, sB0, kB0, vB0); loadE(5, sB1, kB1, vB1);
    loadE(6, sB2, kB2, vB2); loadE(7, sB3, kB3, vB3);

    for (int i = 0; i < d; i += 8) {
        procPair(sA0, kA0, vA0, sA1, kA1, vA1);
        procPair(sA2, kA2, vA2, sA3, kA3, vA3);
        loadE(i + 8,  sA0, kA0, vA0); loadE(i + 9,  sA1, kA1, vA1);
        loadE(i + 10, sA2, kA2, vA2); loadE(i + 11, sA3, kA3, vA3);
        if (i + 4 >= d) break;                 // scalar early-exit: skip dummy B-group
        procPair(sB0, kB0, vB0, sB1, kB1, vB1);
        procPair(sB2, kB2, vB2, sB3, kB3, vB3);
        loadE(i + 12, sB0, kB0, vB0); loadE(i + 13, sB1, kB1, vB1);
        loadE(i + 14, sB2, kB2, vB2); loadE(i + 15, sB3, kB3, vB3);
    }

    const float inv = (den > 0.f) ? 1.f / den : 0.f;   // empty segment -> message 0
    const float2 xv = *(const float2*)(x + (size_t)node * CH + l2);
    const float w0 = (float)a01[0] * inv + xv.x;
    const float w1 = (float)a01[1] * inv + xv.y;

    float sum = w0 + w1;
    #pragma unroll
    for (int off = 32; off; off >>= 1) sum += __shfl_xor(sum, off);
    const float mean = sum * (1.f / 128.f);
    const float c0 = w0 - mean, c1 = w1 - mean;
    float vs = c0 * c0 + c1 * c1;
    #pragma unroll
    for (int off = 32; off; off >>= 1) vs += __shfl_xor(vs, off);
    const float rstd = rsqrtf(vs * (1.f / 128.f) + 1e-5f);

    const float2 g = *(const float2*)(gamma + l2);
    const float2 bt = *(const float2*)(beta + l2);
    float2 ov;
    ov.x = c0 * rstd * g.x + bt.x;
    ov.y = c1 * rstd * g.y + bt.y;
    *(float2*)(o + (size_t)node * CH + l2) = ov;
}

// ============ Fused: weight fp32->f16 convert (192 blocks) + degree histogram ============
__global__ __launch_bounds__(256) void wcvt_hist(
    const float* __restrict__ Wq, const float* __restrict__ Wk, const float* __restrict__ Wv,
    unsigned short* __restrict__ Wb,
    const int* __restrict__ eiAB, const int* __restrict__ eiBA,
    int* __restrict__ degAB, int* __restrict__ degBA,
    int nE, int ebl)
{
    if ((int)blockIdx.x < WCVT_BLOCKS) {
        const int i = blockIdx.x * 256 + threadIdx.x;
        const float* W = (i < CH * CH) ? Wq : (i < 2 * CH * CH) ? Wk : Wv;
        const float s = (i < CH * CH) ? QSCALE : 1.f;
        f16 h = (f16)(W[i & (CH * CH - 1)] * s);
        Wb[i] = __builtin_bit_cast(unsigned short, h);
        return;
    }
    const int b = blockIdx.x - WCVT_BLOCKS;
    const int dir = b >= ebl;
    const int e = ((b - dir * ebl) * 256 + threadIdx.x) * 4;
    if (e >= nE) return;
    const int* ei = dir ? eiBA : eiAB;
    int* deg = dir ? degBA : degAB;
    if (e + 3 < nE) {
        const int4 d4 = *(const int4*)(ei + nE + e);
        atomicAdd(&deg[d4.x], 1); atomicAdd(&deg[d4.y], 1);
        atomicAdd(&deg[d4.z], 1); atomicAdd(&deg[d4.w], 1);
    } else {
        for (int j = e; j < nE; ++j) atomicAdd(&deg[ei[nE + j]], 1);
    }
}

// ======================= CSR scan (both directions per dispatch) =======================
__global__ __launch_bounds__(256) void scan_local(const int* __restrict__ degAB, const int* __restrict__ degBA,
                                                  int* __restrict__ offsAB, int* __restrict__ offsBA,
                                                  int* __restrict__ bsums, int n, int nb)
{
    __shared__ int s[256];
    const int dir = blockIdx.x >= nb;
    const int blk = blockIdx.x - dir * nb;
    const int* deg = dir ? degBA : degAB;
    int* offs = dir ? offsBA : offsAB;
    int* bs = bsums + dir * 256;

    const int t = threadIdx.x;
    const int base = blk * SCAN_BLK + t * 4;
    int v0 = 0, v1 = 0, v2 = 0, v3 = 0;
    if (base + 3 < n) {
        int4 q = *(const int4*)(deg + base);
        v0 = q.x; v1 = q.y; v2 = q.z; v3 = q.w;
    } else {
        if (base + 0 < n) v0 = deg[base + 0];
        if (base + 1 < n) v1 = deg[base + 1];
        if (base + 2 < n) v2 = deg[base + 2];
    }
    const int tsum = v0 + v1 + v2 + v3;
    s[t] = tsum;
    __syncthreads();
    for (int off = 1; off < 256; off <<= 1) {
        int add = (t >= off) ? s[t - off] : 0;
        __syncthreads();
        s[t] += add;
        __syncthreads();
    }
    const int excl = s[t] - tsum;
    if (base + 0 < n) offs[base + 0] = excl;
    if (base + 1 < n) offs[base + 1] = excl + v0;
    if (base + 2 < n) offs[base + 2] = excl + v0 + v1;
    if (base + 3 < n) offs[base + 3] = excl + v0 + v1 + v2;
    if (t == 255) bs[blk] = s[255];
}

// finalize offs and initialize cursor = offs
__global__ __launch_bounds__(256) void add_bsums(int* __restrict__ offsAB, int* __restrict__ offsBA,
                                                 int* __restrict__ curAB, int* __restrict__ curBA,
                                                 const int* __restrict__ bsums, int n, int nbl, int nb)
{
    __shared__ int s[256];
    const int dir = blockIdx.x >= nbl;
    const int blk = blockIdx.x - dir * nbl;
    const int t = threadIdx.x;
    int v = (t < nb) ? bsums[dir * 256 + t] : 0;
    s[t] = v;
    __syncthreads();
    for (int off = 1; off < 256; off <<= 1) {
        int add = (t >= off) ? s[t - off] : 0;
        __syncthreads();
        s[t] += add;
        __syncthreads();
    }
    const int i = blk * 256 + t;
    if (i >= n) return;
    const int bi = i >> 10;                         // SCAN_BLK = 1024
    const int excl = (bi == 0) ? 0 : s[bi - 1];     // inclusive scan shifted
    int* offs = dir ? offsBA : offsAB;
    int* cur  = dir ? curBA  : curAB;
    const int vv = offs[i] + excl;
    offs[i] = vv;
    cur[i] = vv;
}

// ============ Phase 1: QKV projection (f16 MFMA) ∥ csr_fill(BA), 6:1 interleave ============
__global__ __launch_bounds__(256) void qkv_csr1(
    const float* __restrict__ xA, const float* __restrict__ xB,
    const unsigned short* __restrict__ Wb,
    const float* __restrict__ bq, const float* __restrict__ bk, const float* __restrict__ bv,
    unsigned short* __restrict__ Qb, unsigned char* __restrict__ KVb,
    const int* __restrict__ eiBA, const float* __restrict__ sbBA, const float* __restrict__ biasBA,
    int* __restrict__ curBA, int2* __restrict__ edBA,
    int n, int nE, int cblocks, int qblocks)
{
    __shared__ __align__(16) char lds[8192];

    const int bid = blockIdx.x;
    const int mixed = 7 * cblocks;
    int ridx; bool is_csr;
    if (bid < mixed) {
        const int g = bid / 7, r = bid % 7;
        is_csr = (r == 6);
        ridx = is_csr ? g : g * 6 + r;
    } else {
        is_csr = false;
        ridx = 6 * cblocks + (bid - mixed);
    }

    if (is_csr) {
        csr_body(ridx, eiBA, sbBA, biasBA[0], curBA, edBA, nE);
        return;
    }

    // ---- qkv role: 32-row tile, epilogue through one reused 8KB swizzled LDS plane ----
    const int type = ridx & 1;
    const float* x = type ? xB : xA;
    const int bRow = (ridx >> 1) * QROWS;
    const int tid = threadIdx.x;

    #pragma unroll
    for (int j = 0; j < 4; ++j) {
        const int flat16 = j * 256 + tid;
        const int row = flat16 >> 5;
        const int c16 = flat16 & 31;
        float4 v = make_float4(0.f, 0.f, 0.f, 0.f);
        if (bRow + row < n) v = *(const float4*)(x + (size_t)(bRow + row) * CH + c16 * 4);
        const int off = (row * 256 + c16 * 8) ^ ((row & 7) << 4);
        *(uint2*)(lds + off) = make_uint2(pk2(v.x, v.y), pk2(v.z, v.w));
    }
    __syncthreads();

    const int w = tid >> 6, l = tid & 63, lr = l & 15, lg = l >> 4;
    const int colbase = w * 32;

    f32x4 acc[3][2][2];
    #pragma unroll
    for (int p = 0; p < 3; ++p)
        #pragma unroll
        for (int ct = 0; ct < 2; ++ct)
            #pragma unroll
            for (int rt = 0; rt < 2; ++rt)
                acc[p][ct][rt] = (f32x4){0.f, 0.f, 0.f, 0.f};

    #pragma unroll
    for (int kt = 0; kt < 4; ++kt) {
        f16x8 bx[2];
        #pragma unroll
        for (int rt = 0; rt < 2; ++rt) {
            const int row = rt * 16 + lr;
            const int off = (row * 256 + kt * 64 + lg * 16) ^ ((row & 7) << 4);
            bx[rt] = *(const f16x8*)(lds + off);
        }
        #pragma unroll
        for (int p = 0; p < 3; ++p) {
            #pragma unroll
            for (int ct = 0; ct < 2; ++ct) {
                const int ocol = colbase + ct * 16 + lr;
                const f16x8 a = *(const f16x8*)(Wb + ((size_t)p << 14) + (size_t)ocol * CH + kt * 32 + lg * 8);
                #pragma unroll
                for (int rt = 0; rt < 2; ++rt)
                    acc[p][ct][rt] = __builtin_amdgcn_mfma_f32_16x16x32_f16(a, bx[rt], acc[p][ct][rt], 0, 0, 0);
            }
        }
    }

    unsigned short* Qo = Qb + (size_t)type * n * CH;
    unsigned char* KVo = KVb + (size_t)type * n * KVSTRIDE;

    #pragma unroll
    for (int p = 0; p < 3; ++p) {
        __syncthreads();
        const float* bias = (p == 0) ? bq : (p == 1) ? bk : bv;
        #pragma unroll
        for (int ct = 0; ct < 2; ++ct) {
            const int c0 = colbase + ct * 16 + lg * 4;
            float4 bb = *(const float4*)(bias + c0);
            if (p == 0) { bb.x *= QSCALE; bb.y *= QSCALE; bb.z *= QSCALE; bb.w *= QSCALE; }
            #pragma unroll
            for (int rt = 0; rt < 2; ++rt) {
                const int nl = rt * 16 + lr;
                const int swz = (nl & 7) << 4;
                const f32x4 a4 = acc[p][ct][rt];
                if (p == 1) {
                    const int cbk = w * 32 + ct * 16 + lg * 4;
                    int kw = __builtin_amdgcn_cvt_pk_fp8_f32(a4[0] + bb.x, a4[1] + bb.y, 0, false);
                    kw     = __builtin_amdgcn_cvt_pk_fp8_f32(a4[2] + bb.z, a4[3] + bb.w, kw, true);
                    *(unsigned*)(lds + nl * 128 + (cbk ^ swz)) = (unsigned)kw;
                } else {
                    const int cbq = w * 64 + ct * 32 + lg * 8;
                    *(uint2*)(lds + nl * 256 + (cbq ^ swz)) =
                        make_uint2(pk2(a4[0] + bb.x, a4[1] + bb.y), pk2(a4[2] + bb.z, a4[3] + bb.w));
                }
            }
        }
        __syncthreads();
        if (p == 1) {
            const int row = tid >> 3, c = tid & 7;
            const uint4 val = *(const uint4*)(lds + row * 128 + ((c ^ (row & 7)) << 4));
            const int node = bRow + row;
            if (node < n) *(uint4*)(KVo + (size_t)node * KVSTRIDE + c * 16) = val;
        } else {
            #pragma unroll
            for (int j = 0; j < 2; ++j) {
                const int flat = j * 256 + tid;
                const int row = flat >> 4, c16 = flat & 15;
                const uint4 val = *(const uint4*)(lds + row * 256 + ((c16 ^ (row & 7)) << 4));
                const int node = bRow + row;
                if (node < n) {
                    if (p == 0) *(uint4*)(Qo + (size_t)node * CH + c16 * 8) = val;
                    else        *(uint4*)(KVo + (size_t)node * KVSTRIDE + 128 + c16 * 16) = val;
                }
            }
        }
    }
}

// ============ Phase 2: attn(dst A, edges BA) ∥ csr_fill(AB), 25:1 interleave ============
__global__ __launch_bounds__(256) void attn_csr2(
    const unsigned short* __restrict__ Qb, const unsigned char* __restrict__ KVb,
    const float* __restrict__ xA,
    const int* __restrict__ offsBA, const int* __restrict__ degBA, const int2* __restrict__ edBA,
    const float* __restrict__ gamma, const float* __restrict__ beta, float* __restrict__ out,
    const int* __restrict__ eiAB, const float* __restrict__ sbAB, const float* __restrict__ biasAB,
    int* __restrict__ curAB, int2* __restrict__ edAB,
    int n, int nE, int cblocks)
{
    const int bid = blockIdx.x;
    const int mixed = 26 * cblocks;
    int ridx; bool is_csr;
    if (bid < mixed) {
        const int g = bid / 26, r = bid % 26;
        is_csr = (r == 25);
        ridx = is_csr ? g : g * 25 + r;
    } else {
        is_csr = false;
        ridx = 25 * cblocks + (bid - mixed);
    }

    if (is_csr) {
        csr_body(ridx, eiAB, sbAB, biasAB[0], curAB, edAB, nE);
        return;
    }
    // attn dst-type A: Q of A, K/V of B
    attn_body(ridx, Qb, KVb + (size_t)n * KVSTRIDE, xA, offsBA, degBA, edBA, gamma, beta, out, n);
}

// ============ Phase 3: attn(dst B, edges AB) ============
__global__ __launch_bounds__(256) void attn_one(
    const unsigned short* __restrict__ Qb, const unsigned char* __restrict__ KVb,
    const float* __restrict__ xB,
    const int* __restrict__ offsAB, const int* __restrict__ degAB, const int2* __restrict__ edAB,
    const float* __restrict__ gamma, const float* __restrict__ beta, float* __restrict__ out,
    int n)
{
    attn_body(blockIdx.x, Qb + (size_t)n * CH, KVb, xB, offsAB, degAB, edAB,
              gamma, beta, out + (size_t)n * CH, n);
}

extern "C" void kernel_launch(void* const* d_in, const int* in_sizes, int n_in,
                              void* d_out, int out_size, void* d_ws, size_t ws_size,
                              hipStream_t stream)
{
    const float* xA     = (const float*)d_in[0];
    const float* xB     = (const float*)d_in[1];
    const float* Wq     = (const float*)d_in[2];
    const float* bq     = (const float*)d_in[3];
    const float* Wk     = (const float*)d_in[4];
    const float* bk     = (const float*)d_in[5];
    const float* Wv     = (const float*)d_in[6];
    const float* bv     = (const float*)d_in[7];
    const float* gamma  = (const float*)d_in[8];
    const float* beta   = (const float*)d_in[9];
    const float* biasAB = (const float*)d_in[10];
    const float* biasBA = (const float*)d_in[11];
    const float* sbAB   = (const float*)d_in[12];
    const float* sbBA   = (const float*)d_in[13];
    const int*   eiAB   = (const int*)d_in[14];
    const int*   eiBA   = (const int*)d_in[15];

    const int n  = in_sizes[0] / CH;     // 100000
    const int nE = in_sizes[12];         // 1000000
    const size_t NC = (size_t)n * CH;

    // ---- workspace carve-up (16B aligned) ----
    char* p = (char*)d_ws;
    auto carve = [&](size_t bytes) { char* r = p; p += (bytes + 15) & ~(size_t)15; return r; };
    unsigned short* Qb = (unsigned short*)carve(2 * NC * 2);                 // [2][n][128] f16
    unsigned char*  KVb = (unsigned char*)carve((size_t)2 * n * KVSTRIDE);   // [2][n][384B]
    unsigned short* Wb  = (unsigned short*)carve(3 * CH * CH * 2);
    int2* edAB  = (int2*)carve((size_t)nE * 8);
    int2* edBA  = (int2*)carve((size_t)nE * 8);
    int* offsAB = (int*)carve((size_t)n * 4);
    int* offsBA = (int*)carve((size_t)n * 4);
    int* degAB  = (int*)carve((size_t)2 * n * 4);   // degAB,degBA contiguous (one memset)
    int* degBA  = degAB + n;
    int* curAB  = (int*)carve((size_t)n * 4);
    int* curBA  = (int*)carve((size_t)n * 4);
    int* bsums  = (int*)carve(2 * 256 * 4);

    float* out = (float*)d_out;

    (void)hipMemsetAsync(degAB, 0, (size_t)2 * n * sizeof(int), stream);

    const int ebl4 = (nE + 1023) / 1024;
    wcvt_hist<<<WCVT_BLOCKS + 2 * ebl4, 256, 0, stream>>>(Wq, Wk, Wv, Wb,
                                                          eiAB, eiBA, degAB, degBA, nE, ebl4);

    const int nb = (n + SCAN_BLK - 1) / SCAN_BLK;   // 98 <= 256
    scan_local<<<2 * nb, 256, 0, stream>>>(degAB, degBA, offsAB, offsBA, bsums, n, nb);
    const int nbl = (n + 255) / 256;
    add_bsums<<<2 * nbl, 256, 0, stream>>>(offsAB, offsBA, curAB, curBA, bsums, n, nbl, nb);

    const int qblocks = 2 * ((n + QROWS - 1) / QROWS);
    qkv_csr1<<<qblocks + ebl4, 256, 0, stream>>>(xA, xB, Wb, bq, bk, bv, Qb, KVb,
                                                 eiBA, sbBA, biasBA, curBA, edBA,
                                                 n, nE, ebl4, qblocks);

    const int abl = (n + 3) / 4;
    attn_csr2<<<abl + ebl4, 256, 0, stream>>>(Qb, KVb, xA, offsBA, degBA, edBA,
                                              gamma, beta, out,
                                              eiAB, sbAB, biasAB, curAB, edAB,
                                              n, nE, ebl4);

    attn_one<<<abl, 256, 0, stream>>>(Qb, KVb, xB, offsAB, degAB, edAB, gamma, beta, out, n);
}

// Round 18
// 414.343 us; speedup vs baseline: 1.0468x; 1.0468x over previous
//
#include <hip/hip_runtime.h>

#define CH 128
// fold 1/sqrt(32) * log2(e) into Wq/bq so Q·K dots come out in base-2 directly
#define QSCALE (0.17677669529663687f * 1.4426950408889634f)
#define LOG2E 1.4426950408889634f
#define SCAN_BLK 1024
#define KVSTRIDE 384   // per-node row: K (128 fp8 = 128B) | V (128 f16 = 256B)
#define QROWS 32       // qkv tile rows
#define WCVT_BLOCKS 192  // 3*128*128/256

typedef _Float16 f16;
typedef _Float16 f16x2 __attribute__((ext_vector_type(2)));
typedef _Float16 f16x8 __attribute__((ext_vector_type(8)));
typedef __attribute__((ext_vector_type(4))) float f32x4;

__device__ __forceinline__ unsigned pk2(float a, float b) {
    auto h = __builtin_amdgcn_cvt_pkrtz(a, b);     // __fp16 ext_vector(2)
    return __builtin_bit_cast(unsigned, h);
}
__device__ __forceinline__ f16x2 u2h(unsigned u) { return __builtin_bit_cast(f16x2, u); }

template <int CTRL>
__device__ __forceinline__ float dpp_add(float x) {
    const int t = __builtin_amdgcn_update_dpp(0, __builtin_bit_cast(int, x), CTRL, 0xF, 0xF, false);
    return x + __builtin_bit_cast(float, t);
}
// sum over the 16-lane head group (2 ch/lane x 16 lanes = 32 ch)
__device__ __forceinline__ float head_sum(float x) {
    x = dpp_add<0xB1>(x);    // quad_perm(1,0,3,2)
    x = dpp_add<0x4E>(x);    // quad_perm(2,3,0,1)
    x = dpp_add<0x124>(x);   // row_ror:4
    x = dpp_add<0x128>(x);   // row_ror:8
    return x;
}

// ============ Fused: weight fp32->f16 convert (192 blocks) + degree histogram ============
__global__ __launch_bounds__(256) void wcvt_hist(
    const float* __restrict__ Wq, const float* __restrict__ Wk, const float* __restrict__ Wv,
    unsigned short* __restrict__ Wb,
    const int* __restrict__ eiAB, const int* __restrict__ eiBA,
    int* __restrict__ degAB, int* __restrict__ degBA,
    int nE, int ebl)
{
    if ((int)blockIdx.x < WCVT_BLOCKS) {
        const int i = blockIdx.x * 256 + threadIdx.x;
        const float* W = (i < CH * CH) ? Wq : (i < 2 * CH * CH) ? Wk : Wv;
        const float s = (i < CH * CH) ? QSCALE : 1.f;
        f16 h = (f16)(W[i & (CH * CH - 1)] * s);
        Wb[i] = __builtin_bit_cast(unsigned short, h);
        return;
    }
    const int b = blockIdx.x - WCVT_BLOCKS;
    const int dir = b >= ebl;
    const int e = ((b - dir * ebl) * 256 + threadIdx.x) * 4;
    if (e >= nE) return;
    const int* ei = dir ? eiBA : eiAB;
    int* deg = dir ? degBA : degAB;
    if (e + 3 < nE) {
        const int4 d4 = *(const int4*)(ei + nE + e);
        atomicAdd(&deg[d4.x], 1); atomicAdd(&deg[d4.y], 1);
        atomicAdd(&deg[d4.z], 1); atomicAdd(&deg[d4.w], 1);
    } else {
        for (int j = e; j < nE; ++j) atomicAdd(&deg[ei[nE + j]], 1);
    }
}

// ======================= CSR scan (both directions per dispatch) =======================
__global__ __launch_bounds__(256) void scan_local(const int* __restrict__ degAB, const int* __restrict__ degBA,
                                                  int* __restrict__ offsAB, int* __restrict__ offsBA,
                                                  int* __restrict__ bsums, int n, int nb)
{
    __shared__ int s[256];
    const int dir = blockIdx.x >= nb;
    const int blk = blockIdx.x - dir * nb;
    const int* deg = dir ? degBA : degAB;
    int* offs = dir ? offsBA : offsAB;
    int* bs = bsums + dir * 256;

    const int t = threadIdx.x;
    const int base = blk * SCAN_BLK + t * 4;
    int v0 = 0, v1 = 0, v2 = 0, v3 = 0;
    if (base + 3 < n) {
        int4 q = *(const int4*)(deg + base);
        v0 = q.x; v1 = q.y; v2 = q.z; v3 = q.w;
    } else {
        if (base + 0 < n) v0 = deg[base + 0];
        if (base + 1 < n) v1 = deg[base + 1];
        if (base + 2 < n) v2 = deg[base + 2];
    }
    const int tsum = v0 + v1 + v2 + v3;
    s[t] = tsum;
    __syncthreads();
    for (int off = 1; off < 256; off <<= 1) {
        int add = (t >= off) ? s[t - off] : 0;
        __syncthreads();
        s[t] += add;
        __syncthreads();
    }
    const int excl = s[t] - tsum;
    if (base + 0 < n) offs[base + 0] = excl;
    if (base + 1 < n) offs[base + 1] = excl + v0;
    if (base + 2 < n) offs[base + 2] = excl + v0 + v1;
    if (base + 3 < n) offs[base + 3] = excl + v0 + v1 + v2;
    if (t == 255) bs[blk] = s[255];
}

// finalize offs and initialize cursor = offs
__global__ __launch_bounds__(256) void add_bsums(int* __restrict__ offsAB, int* __restrict__ offsBA,
                                                 int* __restrict__ curAB, int* __restrict__ curBA,
                                                 const int* __restrict__ bsums, int n, int nbl, int nb)
{
    __shared__ int s[256];
    const int dir = blockIdx.x >= nbl;
    const int blk = blockIdx.x - dir * nbl;
    const int t = threadIdx.x;
    int v = (t < nb) ? bsums[dir * 256 + t] : 0;
    s[t] = v;
    __syncthreads();
    for (int off = 1; off < 256; off <<= 1) {
        int add = (t >= off) ? s[t - off] : 0;
        __syncthreads();
        s[t] += add;
        __syncthreads();
    }
    const int i = blk * 256 + t;
    if (i >= n) return;
    const int bi = i >> 10;                         // SCAN_BLK = 1024
    const int excl = (bi == 0) ? 0 : s[bi - 1];     // inclusive scan shifted
    int* offs = dir ? offsBA : offsAB;
    int* cur  = dir ? curBA  : curAB;
    const int vv = offs[i] + excl;
    offs[i] = vv;
    cur[i] = vv;
}

// ============ Fused: QKV projection (f16 MFMA) + CSR fill, roles INTERLEAVED 6:1 ============
// csr role: 8 edges/thread (2x R16) -> double atomic/store ILP in the latency-bound scatter.
__global__ __launch_bounds__(256) void qkv_csr(
    const float* __restrict__ xA, const float* __restrict__ xB,
    const unsigned short* __restrict__ Wb,   // [3][128][128] f16 (q*QSCALE,k,v), [outcol][k]
    const float* __restrict__ bq, const float* __restrict__ bk, const float* __restrict__ bv,
    unsigned short* __restrict__ Qb,         // [2][n][128] f16 (pre-scaled)
    unsigned char* __restrict__ KVb,         // [2][n][384B]: K fp8 e4m3 (128B) | V f16 (256B)
    const int* __restrict__ eiAB, const int* __restrict__ eiBA,
    const float* __restrict__ sbAB, const float* __restrict__ sbBA,
    const float* __restrict__ biasAB, const float* __restrict__ biasBA,
    int* __restrict__ curAB, int* __restrict__ curBA,
    int2* __restrict__ edAB, int2* __restrict__ edBA,
    int n, int nE, int cblocks, int ebl)
{
    __shared__ __align__(16) char lds[8192];    // qkv role only

    // ---- role decode: groups of 7 = {6x qkv, 1x csr} while csr blocks remain ----
    const int bid = blockIdx.x;
    const int mixed = 7 * cblocks;
    int ridx; bool is_csr;
    if (bid < mixed) {
        const int g = bid / 7, r = bid % 7;
        is_csr = (r == 6);
        ridx = is_csr ? g : g * 6 + r;
    } else {
        is_csr = false;
        ridx = 6 * cblocks + (bid - mixed);
    }

    if (is_csr) {
        // ---- csr_fill role: scatter (src*KVSTRIDE, (sb+bias)*log2e), 8 edges/thread ----
        const int dir = ridx >= ebl;
        const int e = ((ridx - dir * ebl) * 256 + threadIdx.x) * 8;
        if (e >= nE) return;
        const int* ei = dir ? eiBA : eiAB;
        const float* sb = dir ? sbBA : sbAB;
        const float bia = dir ? biasBA[0] : biasAB[0];
        int* cur = dir ? curBA : curAB;
        int2* ed = dir ? edBA : edAB;
        if (e + 7 < nE) {
            const int4 sa = *(const int4*)(ei + e);
            const int4 sbv = *(const int4*)(ei + e + 4);
            const int4 da = *(const int4*)(ei + nE + e);
            const int4 db = *(const int4*)(ei + nE + e + 4);
            const float4 ba = *(const float4*)(sb + e);
            const float4 bb = *(const float4*)(sb + e + 4);
            int p0 = atomicAdd(&cur[da.x], 1);
            int p1 = atomicAdd(&cur[da.y], 1);
            int p2 = atomicAdd(&cur[da.z], 1);
            int p3 = atomicAdd(&cur[da.w], 1);
            int p4 = atomicAdd(&cur[db.x], 1);
            int p5 = atomicAdd(&cur[db.y], 1);
            int p6 = atomicAdd(&cur[db.z], 1);
            int p7 = atomicAdd(&cur[db.w], 1);
            ed[p0] = make_int2(sa.x * KVSTRIDE, __float_as_int((ba.x + bia) * LOG2E));
            ed[p1] = make_int2(sa.y * KVSTRIDE, __float_as_int((ba.y + bia) * LOG2E));
            ed[p2] = make_int2(sa.z * KVSTRIDE, __float_as_int((ba.z + bia) * LOG2E));
            ed[p3] = make_int2(sa.w * KVSTRIDE, __float_as_int((ba.w + bia) * LOG2E));
            ed[p4] = make_int2(sbv.x * KVSTRIDE, __float_as_int((bb.x + bia) * LOG2E));
            ed[p5] = make_int2(sbv.y * KVSTRIDE, __float_as_int((bb.y + bia) * LOG2E));
            ed[p6] = make_int2(sbv.z * KVSTRIDE, __float_as_int((bb.z + bia) * LOG2E));
            ed[p7] = make_int2(sbv.w * KVSTRIDE, __float_as_int((bb.w + bia) * LOG2E));
        } else {
            for (int j = e; j < nE; ++j) {
                const int pos = atomicAdd(&cur[ei[nE + j]], 1);
                ed[pos] = make_int2(ei[j] * KVSTRIDE, __float_as_int((sb[j] + bia) * LOG2E));
            }
        }
        return;
    }

    // ---- qkv role: 32-row tile, epilogue through one reused 8KB swizzled LDS plane ----
    const int type = ridx & 1;
    const float* x = type ? xB : xA;
    const int bRow = (ridx >> 1) * QROWS;
    const int tid = threadIdx.x;

    #pragma unroll
    for (int j = 0; j < 4; ++j) {
        const int flat16 = j * 256 + tid;
        const int row = flat16 >> 5;
        const int c16 = flat16 & 31;
        float4 v = make_float4(0.f, 0.f, 0.f, 0.f);
        if (bRow + row < n) v = *(const float4*)(x + (size_t)(bRow + row) * CH + c16 * 4);
        const int off = (row * 256 + c16 * 8) ^ ((row & 7) << 4);
        *(uint2*)(lds + off) = make_uint2(pk2(v.x, v.y), pk2(v.z, v.w));
    }
    __syncthreads();

    const int w = tid >> 6, l = tid & 63, lr = l & 15, lg = l >> 4;
    const int colbase = w * 32;

    f32x4 acc[3][2][2];
    #pragma unroll
    for (int p = 0; p < 3; ++p)
        #pragma unroll
        for (int ct = 0; ct < 2; ++ct)
            #pragma unroll
            for (int rt = 0; rt < 2; ++rt)
                acc[p][ct][rt] = (f32x4){0.f, 0.f, 0.f, 0.f};

    #pragma unroll
    for (int kt = 0; kt < 4; ++kt) {
        f16x8 bx[2];
        #pragma unroll
        for (int rt = 0; rt < 2; ++rt) {
            const int row = rt * 16 + lr;
            const int off = (row * 256 + kt * 64 + lg * 16) ^ ((row & 7) << 4);
            bx[rt] = *(const f16x8*)(lds + off);
        }
        #pragma unroll
        for (int p = 0; p < 3; ++p) {
            #pragma unroll
            for (int ct = 0; ct < 2; ++ct) {
                const int ocol = colbase + ct * 16 + lr;
                const f16x8 a = *(const f16x8*)(Wb + ((size_t)p << 14) + (size_t)ocol * CH + kt * 32 + lg * 8);
                #pragma unroll
                for (int rt = 0; rt < 2; ++rt)
                    acc[p][ct][rt] = __builtin_amdgcn_mfma_f32_16x16x32_f16(a, bx[rt], acc[p][ct][rt], 0, 0, 0);
            }
        }
    }

    unsigned short* Qo = Qb + (size_t)type * n * CH;
    unsigned char* KVo = KVb + (size_t)type * n * KVSTRIDE;

    #pragma unroll
    for (int p = 0; p < 3; ++p) {
        __syncthreads();   // prior plane's reads (or x-staging reads) complete
        const float* bias = (p == 0) ? bq : (p == 1) ? bk : bv;
        #pragma unroll
        for (int ct = 0; ct < 2; ++ct) {
            const int c0 = colbase + ct * 16 + lg * 4;
            float4 bb = *(const float4*)(bias + c0);
            if (p == 0) { bb.x *= QSCALE; bb.y *= QSCALE; bb.z *= QSCALE; bb.w *= QSCALE; }
            #pragma unroll
            for (int rt = 0; rt < 2; ++rt) {
                const int nl = rt * 16 + lr;
                const int swz = (nl & 7) << 4;
                const f32x4 a4 = acc[p][ct][rt];
                if (p == 1) {      // K plane: fp8, 128B rows
                    const int cbk = w * 32 + ct * 16 + lg * 4;
                    int kw = __builtin_amdgcn_cvt_pk_fp8_f32(a4[0] + bb.x, a4[1] + bb.y, 0, false);
                    kw     = __builtin_amdgcn_cvt_pk_fp8_f32(a4[2] + bb.z, a4[3] + bb.w, kw, true);
                    *(unsigned*)(lds + nl * 128 + (cbk ^ swz)) = (unsigned)kw;
                } else {           // Q / V plane: f16, 256B rows
                    const int cbq = w * 64 + ct * 32 + lg * 8;
                    *(uint2*)(lds + nl * 256 + (cbq ^ swz)) =
                        make_uint2(pk2(a4[0] + bb.x, a4[1] + bb.y), pk2(a4[2] + bb.z, a4[3] + bb.w));
                }
            }
        }
        __syncthreads();
        if (p == 1) {              // K: 4KB -> 1 store round
            const int row = tid >> 3, c = tid & 7;
            const uint4 val = *(const uint4*)(lds + row * 128 + ((c ^ (row & 7)) << 4));
            const int node = bRow + row;
            if (node < n) *(uint4*)(KVo + (size_t)node * KVSTRIDE + c * 16) = val;
        } else {                   // Q / V: 8KB -> 2 store rounds
            #pragma unroll
            for (int j = 0; j < 2; ++j) {
                const int flat = j * 256 + tid;
                const int row = flat >> 4, c16 = flat & 15;
                const uint4 val = *(const uint4*)(lds + row * 256 + ((c16 ^ (row & 7)) << 4));
                const int node = bRow + row;
                if (node < n) {
                    if (p == 0) *(uint4*)(Qo + (size_t)node * CH + c16 * 8) = val;
                    else        *(uint4*)(KVo + (size_t)node * KVSTRIDE + 128 + c16 * 16) = val;
                }
            }
        }
    }
}

// ======================= Fused per-node attention + residual + LayerNorm =======================
// R10 structure: 1 node/wave, 2 ch/lane, 8-deep ping-pong prefetch, wave-uniform branchy
// loads, scalar mid-loop early-exit (effective tail stride 4). K fp8 e4m3, V f16. Base-2
// online softmax with defer-max. Degree term cancels in LN mean subtraction.
__global__ __launch_bounds__(256) void attn_node(
    const unsigned short* __restrict__ Qb,   // [2][n][128] f16 pre-scaled
    const unsigned char* __restrict__ KVb,   // [2][n][384B]
    const float* __restrict__ xA, const float* __restrict__ xB,
    const int* __restrict__ offsAB, const int* __restrict__ offsBA,
    const int* __restrict__ degAB, const int* __restrict__ degBA,
    const int2* __restrict__ edAB, const int2* __restrict__ edBA,
    const float* __restrict__ gamma, const float* __restrict__ beta,
    float* __restrict__ out, int n, int abl)
{
    const int dir = blockIdx.x >= abl;       // 0: dst type A (edges BA), 1: dst type B (edges AB)
    const int node = (blockIdx.x - dir * abl) * 4 + (threadIdx.x >> 6);
    if (node >= n) return;
    const int l = threadIdx.x & 63;
    const int l2 = l * 2;

    const unsigned short* Q = Qb + (size_t)dir * n * CH;
    const unsigned char* KV = KVb + (size_t)(1 - dir) * n * KVSTRIDE;
    const float* x = dir ? xB : xA;
    const int* offs = dir ? offsAB : offsBA;
    const int* deg  = dir ? degAB  : degBA;
    const int2* ed  = dir ? edAB   : edBA;
    float* o = out + (size_t)dir * n * CH;

    const f16x2 qp = u2h(*(const unsigned*)(Q + (size_t)node * CH + l2));
    const float qf0 = (float)qp[0], qf1 = (float)qp[1];

    const int beg = __builtin_amdgcn_readfirstlane(offs[node]);
    const int d   = __builtin_amdgcn_readfirstlane(deg[node]);

    float m = -3.0e38f, den = 0.f;
    f16x2 a01 = (f16x2){(f16)0.f, (f16)0.f};

    auto loadE = [&](int i, float& sbf, unsigned& kc, unsigned& vc) {
        if (i < d) {                                   // wave-uniform -> scalar branch
            const int2 e = ed[beg + i];
            sbf = __int_as_float(e.y);
            const unsigned b = (unsigned)e.x;          // premultiplied byte offset
            kc = *(const unsigned short*)(KV + b + l2);        // 2 fp8 (channels 2l,2l+1)
            vc = *(const unsigned*)(KV + b + 128 + l2 * 2);    // 2 f16
        } else {
            sbf = __int_as_float((int)0xFF800000u);    // -inf -> zero contribution
            kc = 0; vc = 0;
        }
    };

    auto procPair = [&](float sf0, unsigned k0, unsigned v0,
                        float sf1, unsigned k1, unsigned v1) {
        const auto kf0 = __builtin_amdgcn_cvt_pk_f32_fp8((int)k0, false);
        const auto kf1 = __builtin_amdgcn_cvt_pk_f32_fp8((int)k1, false);
        float sa = head_sum(fmaf(qf0, kf0[0], qf1 * kf0[1])) + sf0;
        float sb = head_sum(fmaf(qf0, kf1[0], qf1 * kf1[1])) + sf1;
        const float pm = fmaxf(sa, sb);
        if (!__all(pm <= m + 8.f)) {           // defer-max
            const float mn = fmaxf(m, pm);
            const float sc = exp2f(m - mn);
            den *= sc;
            a01 *= u2h(pk2(sc, sc));
            m = mn;
        }
        const float ea = exp2f(sa - m);
        const float eb = exp2f(sb - m);
        den += ea + eb;
        a01 += u2h(pk2(ea, ea)) * u2h(v0);
        a01 += u2h(pk2(eb, eb)) * u2h(v1);
    };

    float sA0, sA1, sA2, sA3, sB0, sB1, sB2, sB3;
    unsigned kA0, kA1, kA2, kA3, kB0, kB1, kB2, kB3;
    unsigned vA0, vA1, vA2, vA3, vB0, vB1, vB2, vB3;
    loadE(0, sA0, kA0, vA0); loadE(1, sA1, kA1, vA1);
    loadE(2, sA2, kA2, vA2); loadE(3, sA3, kA3, vA3);
    loadE(4, sB0, kB0, vB0); loadE(5, sB1, kB1, vB1);
    loadE(6, sB2, kB2, vB2); loadE(7, sB3, kB3, vB3);

    for (int i = 0; i < d; i += 8) {
        procPair(sA0, kA0, vA0, sA1, kA1, vA1);
        procPair(sA2, kA2, vA2, sA3, kA3, vA3);
        loadE(i + 8,  sA0, kA0, vA0); loadE(i + 9,  sA1, kA1, vA1);
        loadE(i + 10, sA2, kA2, vA2); loadE(i + 11, sA3, kA3, vA3);
        if (i + 4 >= d) break;                 // scalar early-exit: skip dummy B-group
        procPair(sB0, kB0, vB0, sB1, kB1, vB1);
        procPair(sB2, kB2, vB2, sB3, kB3, vB3);
        loadE(i + 12, sB0, kB0, vB0); loadE(i + 13, sB1, kB1, vB1);
        loadE(i + 14, sB2, kB2, vB2); loadE(i + 15, sB3, kB3, vB3);
    }

    const float inv = (den > 0.f) ? 1.f / den : 0.f;   // empty segment -> message 0
    const float2 xv = *(const float2*)(x + (size_t)node * CH + l2);
    const float w0 = (float)a01[0] * inv + xv.x;
    const float w1 = (float)a01[1] * inv + xv.y;

    float sum = w0 + w1;
    #pragma unroll
    for (int off = 32; off; off >>= 1) sum += __shfl_xor(sum, off);
    const float mean = sum * (1.f / 128.f);
    const float c0 = w0 - mean, c1 = w1 - mean;
    float vs = c0 * c0 + c1 * c1;
    #pragma unroll
    for (int off = 32; off; off >>= 1) vs += __shfl_xor(vs, off);
    const float rstd = rsqrtf(vs * (1.f / 128.f) + 1e-5f);

    const float2 g = *(const float2*)(gamma + l2);
    const float2 bt = *(const float2*)(beta + l2);
    float2 ov;
    ov.x = c0 * rstd * g.x + bt.x;
    ov.y = c1 * rstd * g.y + bt.y;
    *(float2*)(o + (size_t)node * CH + l2) = ov;
}

extern "C" void kernel_launch(void* const* d_in, const int* in_sizes, int n_in,
                              void* d_out, int out_size, void* d_ws, size_t ws_size,
                              hipStream_t stream)
{
    const float* xA     = (const float*)d_in[0];
    const float* xB     = (const float*)d_in[1];
    const float* Wq     = (const float*)d_in[2];
    const float* bq     = (const float*)d_in[3];
    const float* Wk     = (const float*)d_in[4];
    const float* bk     = (const float*)d_in[5];
    const float* Wv     = (const float*)d_in[6];
    const float* bv     = (const float*)d_in[7];
    const float* gamma  = (const float*)d_in[8];
    const float* beta   = (const float*)d_in[9];
    const float* biasAB = (const float*)d_in[10];
    const float* biasBA = (const float*)d_in[11];
    const float* sbAB   = (const float*)d_in[12];
    const float* sbBA   = (const float*)d_in[13];
    const int*   eiAB   = (const int*)d_in[14];
    const int*   eiBA   = (const int*)d_in[15];

    const int n  = in_sizes[0] / CH;     // 100000
    const int nE = in_sizes[12];         // 1000000
    const size_t NC = (size_t)n * CH;

    // ---- workspace carve-up (16B aligned) ----
    char* p = (char*)d_ws;
    auto carve = [&](size_t bytes) { char* r = p; p += (bytes + 15) & ~(size_t)15; return r; };
    unsigned short* Qb = (unsigned short*)carve(2 * NC * 2);                 // [2][n][128] f16
    unsigned char*  KVb = (unsigned char*)carve((size_t)2 * n * KVSTRIDE);   // [2][n][384B]
    unsigned short* Wb  = (unsigned short*)carve(3 * CH * CH * 2);
    int2* edAB  = (int2*)carve((size_t)nE * 8);
    int2* edBA  = (int2*)carve((size_t)nE * 8);
    int* offsAB = (int*)carve((size_t)n * 4);
    int* offsBA = (int*)carve((size_t)n * 4);
    int* degAB  = (int*)carve((size_t)2 * n * 4);   // degAB,degBA contiguous (one memset)
    int* degBA  = degAB + n;
    int* curAB  = (int*)carve((size_t)n * 4);
    int* curBA  = (int*)carve((size_t)n * 4);
    int* bsums  = (int*)carve(2 * 256 * 4);

    float* out = (float*)d_out;

    (void)hipMemsetAsync(degAB, 0, (size_t)2 * n * sizeof(int), stream);

    const int ebl4 = (nE + 1023) / 1024;
    wcvt_hist<<<WCVT_BLOCKS + 2 * ebl4, 256, 0, stream>>>(Wq, Wk, Wv, Wb,
                                                          eiAB, eiBA, degAB, degBA, nE, ebl4);

    const int nb = (n + SCAN_BLK - 1) / SCAN_BLK;   // 98 <= 256
    scan_local<<<2 * nb, 256, 0, stream>>>(degAB, degBA, offsAB, offsBA, bsums, n, nb);
    const int nbl = (n + 255) / 256;
    add_bsums<<<2 * nbl, 256, 0, stream>>>(offsAB, offsBA, curAB, curBA, bsums, n, nbl, nb);

    const int ebl8 = (nE + 2047) / 2048;            // csr: 8 edges/thread
    const int qblocks = 2 * ((n + QROWS - 1) / QROWS);
    const int cblocks = 2 * ebl8;
    qkv_csr<<<qblocks + cblocks, 256, 0, stream>>>(xA, xB, Wb, bq, bk, bv, Qb, KVb,
                                                   eiAB, eiBA, sbAB, sbBA, biasAB, biasBA,
                                                   curAB, curBA, edAB, edBA,
                                                   n, nE, cblocks, ebl8);

    const int abl = (n + 3) / 4;
    attn_node<<<2 * abl, 256, 0, stream>>>(Qb, KVb, xA, xB, offsAB, offsBA, degAB, degBA,
                                           edAB, edBA, gamma, beta, out, n, abl);
}